// Round 4
// baseline (194.721 us; speedup 1.0000x reference)
//
#include <hip/hip_runtime.h>
#include <stdint.h>

// Sizes fixed by the problem
#define BSZ 4
#define NSEQ 512
#define DMOD 1024
#define NH 16
#define HD 64

typedef __attribute__((ext_vector_type(8))) short bf16x8;
typedef __attribute__((ext_vector_type(4))) float f32x4;

__device__ __forceinline__ unsigned short f2bf(float f) {
    union { float f; uint32_t u; } v; v.f = f;
    uint32_t u = v.u;
    u += 0x7FFFu + ((u >> 16) & 1u);   // RNE
    return (unsigned short)(u >> 16);
}

__device__ __forceinline__ void gload_lds16(const unsigned short* g, unsigned short* l) {
    __builtin_amdgcn_global_load_lds(
        (const __attribute__((address_space(1))) void*)g,
        (__attribute__((address_space(3))) void*)l, 16, 0, 0);
}

// raw barrier that does NOT drain vmcnt (in-flight global loads survive)
#define LGKM_BAR() do { \
    asm volatile("s_waitcnt lgkmcnt(0)" ::: "memory"); \
    __builtin_amdgcn_sched_barrier(0); \
    __builtin_amdgcn_s_barrier(); \
    __builtin_amdgcn_sched_barrier(0); } while (0)

// ============ A: prep — cvt x, transpose-cvt wq/wk, wv2/bv2 ============
__global__ __launch_bounds__(256) void k_prep(
        const float* __restrict__ x, const float* __restrict__ wq, const float* __restrict__ wk,
        const float* __restrict__ wv, const float* __restrict__ bv, const float* __restrict__ wo,
        unsigned short* __restrict__ xb, unsigned short* __restrict__ wqt,
        unsigned short* __restrict__ wkt, float* __restrict__ wv2t, float* __restrict__ bv2) {
    __shared__ float t[32][33];
    int bx = blockIdx.x, tid = threadIdx.x;
    if (bx < 2048) {
        int i = bx * 256 + tid;
        float4 v = ((const float4*)x)[i];
        ushort4 o; o.x = f2bf(v.x); o.y = f2bf(v.y); o.z = f2bf(v.z); o.w = f2bf(v.w);
        ((ushort4*)xb)[i] = o;
    } else if (bx < 4096) {
        int g = bx - 2048; int z = g >> 10; g &= 1023;
        const float* src = z ? wk : wq;
        unsigned short* dst = z ? wkt : wqt;
        int be = (g & 31) * 32, bc = (g >> 5) * 32;
        int tx = tid & 31, ty = tid >> 5;
        #pragma unroll
        for (int yy = 0; yy < 32; yy += 8)
            t[ty + yy][tx] = src[(size_t)(be + ty + yy) * DMOD + bc + tx];
        __syncthreads();
        #pragma unroll
        for (int yy = 0; yy < 32; yy += 8)
            dst[(size_t)(bc + ty + yy) * DMOD + be + tx] = f2bf(t[tx][ty + yy]);
    } else {
        int g = bx - 4096;
        int grp = tid >> 6, l = tid & 63;
        int e = g * 4 + grp;
        float out = 0.f;
        #pragma unroll
        for (int it = 0; it < 16; ++it) {
            float v = wv[(size_t)e * DMOD + it * 64 + l] * wo[it * 64 + l];
            #pragma unroll
            for (int off = 1; off < 64; off <<= 1) v += __shfl_xor(v, off, 64);
            if (l == it) out = v;
        }
        if (l < 16) wv2t[l * DMOD + e] = out;
        if (g == 0 && grp == 0) {
            float ob = 0.f;
            #pragma unroll
            for (int it = 0; it < 16; ++it) {
                float v = bv[it * 64 + l] * wo[it * 64 + l];
                #pragma unroll
                for (int off = 1; off < 64; off <<= 1) v += __shfl_xor(v, off, 64);
                if (l == it) ob = v;
            }
            if (l < 16) bv2[l] = ob;
        }
    }
}

// ============ B: mid — u projection + Q/K MFMA GEMM, 128x128 m97 structure ============
__global__ __launch_bounds__(256, 3) void k_mid(
        const float* __restrict__ x, const float* __restrict__ wv2t, const float* __restrict__ bv2,
        const unsigned short* __restrict__ xb, const unsigned short* __restrict__ wqt,
        const unsigned short* __restrict__ wkt, const float* __restrict__ bq,
        const float* __restrict__ bk, float* __restrict__ u,
        unsigned short* __restrict__ qT, unsigned short* __restrict__ kT) {
    __shared__ unsigned short lA[128 * 64];
    __shared__ unsigned short lB[128 * 64];
    int bx = blockIdx.x, tid = threadIdx.x;
    if (bx >= 256) {
        int wave = (bx - 256) * 4 + (tid >> 6);
        int l = tid & 63;
        int b = wave >> 9, j = wave & 511;
        const float* xr = x + (size_t)(b * NSEQ + j) * DMOD;
        float p[16];
        #pragma unroll
        for (int h = 0; h < 16; ++h) p[h] = 0.f;
        for (int it = 0; it < 16; ++it) {
            int e = l + it * 64;
            float xv = xr[e];
            #pragma unroll
            for (int h = 0; h < 16; ++h) p[h] += xv * wv2t[h * DMOD + e];
        }
        #pragma unroll
        for (int h = 0; h < 16; ++h) {
            #pragma unroll
            for (int off = 1; off < 64; off <<= 1) p[h] += __shfl_xor(p[h], off, 64);
        }
        float out = 0.f;
        #pragma unroll
        for (int h = 0; h < 16; ++h) if (l == h) out = p[h] + bv2[h];
        if (l < 16) u[(b * 16 + l) * NSEQ + j] = out;
        return;
    }
    int g = bx;
    int mt = g & 15, nt8 = (g >> 4) & 7, z = g >> 7;
    const unsigned short* Wt = z ? wkt : wqt;
    const float* bias = z ? bk : bq;
    unsigned short* outT = z ? kT : qT;
    float scale = z ? 1.f : 0.125f;   // fold /sqrt(HD)=1/8 into q
    int m0 = mt * 128, n0 = nt8 * 128;
    int w = tid >> 6, lane = tid & 63;
    int wr = w >> 1, wc = w & 1;
    int quad = lane >> 4, cs = lane & 15;
    int l8 = lane >> 3, l7 = lane & 7;
    int sg = l7 ^ l8;                  // pre-swizzled source granule

    f32x4 acc[4][4];
    #pragma unroll
    for (int mi = 0; mi < 4; ++mi)
        #pragma unroll
        for (int ni = 0; ni < 4; ++ni) acc[mi][ni] = (f32x4){0.f, 0.f, 0.f, 0.f};

    for (int kc = 0; kc < 16; ++kc) {
        int k0 = kc * 64;
        #pragma unroll
        for (int q = 0; q < 4; ++q) {
            int row = w * 32 + q * 8 + l8;      // row&7 == l8 (base multiple of 8)
            gload_lds16(xb + (size_t)(m0 + row) * DMOD + k0 + sg * 8,
                        &lA[(w * 32 + q * 8) * 64]);
            gload_lds16(Wt + (size_t)(n0 + row) * DMOD + k0 + sg * 8,
                        &lB[(w * 32 + q * 8) * 64]);
        }
        __syncthreads();
        #pragma unroll
        for (int ks = 0; ks < 2; ++ks) {
            bf16x8 af[4], bfr[4];
            #pragma unroll
            for (int mi = 0; mi < 4; ++mi) {
                int row = wr * 64 + mi * 16 + cs;
                int gq = (ks * 4 + quad) ^ (row & 7);
                af[mi] = *(const bf16x8*)&lA[row * 64 + gq * 8];
            }
            #pragma unroll
            for (int ni = 0; ni < 4; ++ni) {
                int row = wc * 64 + ni * 16 + cs;
                int gq = (ks * 4 + quad) ^ (row & 7);
                bfr[ni] = *(const bf16x8*)&lB[row * 64 + gq * 8];
            }
            #pragma unroll
            for (int mi = 0; mi < 4; ++mi)
                #pragma unroll
                for (int ni = 0; ni < 4; ++ni)
                    acc[mi][ni] = __builtin_amdgcn_mfma_f32_16x16x32_bf16(
                        af[mi], bfr[ni], acc[mi][ni], 0, 0, 0);
        }
        __syncthreads();
    }
    #pragma unroll
    for (int ni = 0; ni < 4; ++ni) {
        int n = n0 + wc * 64 + ni * 16 + cs;
        int h = n >> 6, d = n & 63;
        float bvv = bias[n];
        #pragma unroll
        for (int mi = 0; mi < 4; ++mi) {
            #pragma unroll
            for (int rr = 0; rr < 4; ++rr) {
                int mg = m0 + wr * 64 + mi * 16 + quad * 4 + rr;
                int b = mg >> 9, i = mg & 511;
                outT[(size_t)((b * 16 + h) * NSEQ + i) * HD + d] =
                    f2bf((acc[mi][ni][rr] + bvv) * scale);
            }
        }
    }
}

// ============ C: fused attn — both head-groups per block (r/mask staged ONCE) ============
// grid (32 it, 8 jc, 4 b), 512 thr = 8 waves; wave w covers h = w and h = 8+w in hg loop.
// r-tile + mask packed as float4 (r0,r1,r2,maskf) in LDS; staging loads issued OLDEST;
// per-head Q/K/bias/u register loads follow; lgkm-only raw barrier (no vmcnt drain).
__global__ __launch_bounds__(512, 4) void k_attn(
        const unsigned short* __restrict__ qT, const unsigned short* __restrict__ kT,
        const float* __restrict__ bias, const int* __restrict__ mask,
        const float* __restrict__ u, const float* __restrict__ r,
        float* __restrict__ spart, float* __restrict__ P) {
    __shared__ float rT4[16 * 64 * 4];
    int tid = threadIdx.x;
    int w = tid >> 6, lane = tid & 63;
    int quad = lane >> 4, col = lane & 15;
    int it = blockIdx.x, jc = blockIdx.y, b = blockIdx.z;
    int i0 = it * 16, j0 = jc * 64;

    // ---- staging source loads FIRST (oldest in flight) ----
    float s0[2], s1[2], s2[2], smf[2];
    const float* rbase = r + (size_t)b * 3 * NSEQ * NSEQ;
    const int* mrow = mask + (size_t)b * NSEQ * NSEQ;
    #pragma unroll
    for (int t = 0; t < 2; ++t) {
        int slot = t * 512 + tid;
        int il = slot >> 6, jl = slot & 63;
        size_t off = (size_t)(i0 + il) * NSEQ + j0 + jl;
        s0[t] = rbase[off];
        s1[t] = rbase[(size_t)NSEQ * NSEQ + off];
        s2[t] = rbase[2 * (size_t)NSEQ * NSEQ + off];
        smf[t] = (float)mrow[off];
    }
    #pragma unroll
    for (int t = 0; t < 2; ++t) {
        int slot = t * 512 + tid;
        float4 pk; pk.x = s0[t]; pk.y = s1[t]; pk.z = s2[t]; pk.w = smf[t];
        *(float4*)&rT4[slot * 4] = pk;
    }

    // lgkm-only barrier: LDS visibility guaranteed; later global loads overlap freely
    LGKM_BAR();

    #pragma unroll
    for (int hg = 0; hg < 2; ++hg) {
        int bh = b * 16 + hg * 8 + w;

        const unsigned short* qbase = qT + ((size_t)(bh * NSEQ + i0 + col)) * HD + quad * 8;
        bf16x8 a0 = *(const bf16x8*)qbase;
        bf16x8 a1 = *(const bf16x8*)(qbase + 32);

        bf16x8 kf0[4], kf1[4];
        #pragma unroll
        for (int jt = 0; jt < 4; ++jt) {
            const unsigned short* kbase =
                kT + ((size_t)(bh * NSEQ + j0 + jt * 16 + col)) * HD + quad * 8;
            kf0[jt] = *(const bf16x8*)kbase;
            kf1[jt] = *(const bf16x8*)(kbase + 32);
        }
        const float* brow = bias + (size_t)bh * NSEQ * NSEQ;
        float bvv[16];
        #pragma unroll
        for (int jt = 0; jt < 4; ++jt) {
            int j = j0 + jt * 16 + col;
            #pragma unroll
            for (int rr = 0; rr < 4; ++rr) {
                int i = i0 + quad * 4 + rr;
                bvv[jt * 4 + rr] = __builtin_nontemporal_load(&brow[(size_t)i * NSEQ + j]);
            }
        }
        const float* ub = u + (size_t)bh * NSEQ;
        float uvv[4];
        #pragma unroll
        for (int jt = 0; jt < 4; ++jt) uvv[jt] = ub[j0 + jt * 16 + col];

        float sp[4] = {0.f, 0.f, 0.f, 0.f};
        float pc0[4] = {0.f, 0.f, 0.f, 0.f};
        float pc1[4] = {0.f, 0.f, 0.f, 0.f};
        float pc2[4] = {0.f, 0.f, 0.f, 0.f};
        #pragma unroll
        for (int jt = 0; jt < 4; ++jt) {
            f32x4 acc = (f32x4){0.f, 0.f, 0.f, 0.f};
            acc = __builtin_amdgcn_mfma_f32_16x16x32_bf16(a0, kf0[jt], acc, 0, 0, 0);
            acc = __builtin_amdgcn_mfma_f32_16x16x32_bf16(a1, kf1[jt], acc, 0, 0, 0);
            float uv = uvv[jt];
            int jl = jt * 16 + col;
            #pragma unroll
            for (int rr = 0; rr < 4; ++rr) {
                int il = quad * 4 + rr;
                float4 v = *(const float4*)&rT4[(il * 64 + jl) * 4];
                float lg = acc[rr] + bvv[jt * 4 + rr];
                float e = __expf(lg) * v.w;          // v.w = mask (0/1)
                sp[rr] += e;
                float eu = e * uv;
                pc0[rr] += eu * v.x;
                pc1[rr] += eu * v.y;
                pc2[rr] += eu * v.z;
            }
        }
        // reduce over the 16 col-lanes
        #pragma unroll
        for (int rr = 0; rr < 4; ++rr) {
            #pragma unroll
            for (int off = 1; off < 16; off <<= 1) {
                sp[rr]  += __shfl_xor(sp[rr], off, 64);
                pc0[rr] += __shfl_xor(pc0[rr], off, 64);
                pc1[rr] += __shfl_xor(pc1[rr], off, 64);
                pc2[rr] += __shfl_xor(pc2[rr], off, 64);
            }
        }
        if (col == 0) {
            #pragma unroll
            for (int rr = 0; rr < 4; ++rr) {
                int il = quad * 4 + rr;
                spart[((size_t)bh * NSEQ + i0 + il) * 8 + jc] = sp[rr];
                // P layout: [bh][it][il][jc][3] — jc innermost so k_final reads contiguous
                size_t pb = ((((size_t)bh * 32 + it) * 16 + il) * 8 + jc) * 3;
                P[pb + 0] = pc0[rr];
                P[pb + 1] = pc1[rr];
                P[pb + 2] = pc2[rr];
            }
        }
    }
}

// ============ D: final — sinv + force (coalesced P reads) ============
// grid 128 = (b 4) x (it 32); block 256: il = tid&15 (contiguous P), h = tid>>4.
__global__ __launch_bounds__(256) void k_final(
        const float* __restrict__ spart, const float* __restrict__ P,
        const float* __restrict__ bo, float* __restrict__ out) {
    __shared__ float part[4][16][3];
    int bx = blockIdx.x;
    int b = bx >> 5, it = bx & 31;
    int tid = threadIdx.x;
    int il = tid & 15, h = tid >> 4;
    int w = tid >> 6;
    int bh = b * 16 + h;
    int i = it * 16 + il;
    const float* sprow = spart + ((size_t)bh * NSEQ + i) * 8;
    float4 sa = *(const float4*)sprow;
    float4 sb = *(const float4*)(sprow + 4);
    float s = sa.x + sa.y + sa.z + sa.w + sb.x + sb.y + sb.z + sb.w;
    float sinv = (s > 0.f) ? 1.f / s : 0.f;
    const float* pbase = P + (((size_t)bh * 32 + it) * 16 + il) * 24;
    float f[3] = {0.f, 0.f, 0.f};
    #pragma unroll
    for (int q = 0; q < 6; ++q) {
        float4 v = *(const float4*)(pbase + q * 4);
        f[(q * 4 + 0) % 3] += v.x;
        f[(q * 4 + 1) % 3] += v.y;
        f[(q * 4 + 2) % 3] += v.z;
        f[(q * 4 + 3) % 3] += v.w;
    }
    f[0] *= sinv; f[1] *= sinv; f[2] *= sinv;
    #pragma unroll
    for (int c = 0; c < 3; ++c) {
        f[c] += __shfl_xor(f[c], 16, 64);
        f[c] += __shfl_xor(f[c], 32, 64);
    }
    if ((tid & 48) == 0) {      // lane < 16 in each wave: holds sum over its 4 h values
        part[w][il][0] = f[0]; part[w][il][1] = f[1]; part[w][il][2] = f[2];
    }
    __syncthreads();
    if (tid < 16) {
        float bov = bo[0];
        float o0 = part[0][tid][0] + part[1][tid][0] + part[2][tid][0] + part[3][tid][0];
        float o1 = part[0][tid][1] + part[1][tid][1] + part[2][tid][1] + part[3][tid][1];
        float o2 = part[0][tid][2] + part[1][tid][2] + part[2][tid][2] + part[3][tid][2];
        size_t row = (size_t)b * NSEQ + it * 16 + tid;
        out[row * 3 + 0] = o0 + bov;
        out[row * 3 + 1] = o1 + bov;
        out[row * 3 + 2] = o2 + bov;
    }
}

extern "C" void kernel_launch(void* const* d_in, const int* in_sizes, int n_in,
                              void* d_out, int out_size, void* d_ws, size_t ws_size,
                              hipStream_t stream) {
    const float* x    = (const float*)d_in[0];
    const float* rr   = (const float*)d_in[1];
    const float* bias = (const float*)d_in[2];
    const int*   mask = (const int*)d_in[3];
    const float* wq   = (const float*)d_in[4];
    const float* bq   = (const float*)d_in[5];
    const float* wk   = (const float*)d_in[6];
    const float* bk   = (const float*)d_in[7];
    const float* wv   = (const float*)d_in[8];
    const float* bv   = (const float*)d_in[9];
    const float* wo   = (const float*)d_in[10];
    const float* bo   = (const float*)d_in[11];
    float* out = (float*)d_out;

    char* ws = (char*)d_ws;
    unsigned short* xb    = (unsigned short*)(ws + 0);          //  4 MiB
    unsigned short* wqt   = (unsigned short*)(ws + 4194304);    //  2 MiB
    unsigned short* wkt   = (unsigned short*)(ws + 6291456);    //  2 MiB
    float*          wv2t  = (float*)(ws + 8388608);             //  64 KiB
    float*          bv2   = (float*)(ws + 8454144);             //  256 B
    float*          u     = (float*)(ws + 8454400);             //  128 KiB
    unsigned short* qT    = (unsigned short*)(ws + 8585472);    //  4 MiB
    unsigned short* kT    = (unsigned short*)(ws + 12779776);   //  4 MiB
    float*          spart = (float*)(ws + 16974080);            //  1 MiB
    float*          P     = (float*)(ws + 18022656);            //  3 MiB
    // total ~21.2 MB

    k_prep<<<4352, 256, 0, stream>>>(x, wq, wk, wv, bv, wo, xb, wqt, wkt, wv2t, bv2);
    k_mid<<<768, 256, 0, stream>>>(x, wv2t, bv2, xb, wqt, wkt, bq, bk, u, qT, kT);
    k_attn<<<dim3(32, 8, 4), 512, 0, stream>>>(qT, kT, bias, mask, u, rr, spart, P);
    k_final<<<128, 256, 0, stream>>>(spart, P, bo, out);
}

// Round 5
// 186.726 us; speedup vs baseline: 1.0428x; 1.0428x over previous
//
#include <hip/hip_runtime.h>
#include <stdint.h>

// Sizes fixed by the problem
#define BSZ 4
#define NSEQ 512
#define DMOD 1024
#define NH 16
#define HD 64

typedef __attribute__((ext_vector_type(8))) short bf16x8;
typedef __attribute__((ext_vector_type(4))) float f32x4;

__device__ __forceinline__ unsigned short f2bf(float f) {
    union { float f; uint32_t u; } v; v.f = f;
    uint32_t u = v.u;
    u += 0x7FFFu + ((u >> 16) & 1u);   // RNE
    return (unsigned short)(u >> 16);
}

__device__ __forceinline__ void gload_lds16(const unsigned short* g, unsigned short* l) {
    __builtin_amdgcn_global_load_lds(
        (const __attribute__((address_space(1))) void*)g,
        (__attribute__((address_space(3))) void*)l, 16, 0, 0);
}

__device__ __forceinline__ void gload_lds16f(const float* g, float* l) {
    __builtin_amdgcn_global_load_lds(
        (const __attribute__((address_space(1))) void*)g,
        (__attribute__((address_space(3))) void*)l, 16, 0, 0);
}

// raw barrier that does NOT drain vmcnt (in-flight global loads survive)
#define LGKM_BAR() do { \
    asm volatile("s_waitcnt lgkmcnt(0)" ::: "memory"); \
    __builtin_amdgcn_sched_barrier(0); \
    __builtin_amdgcn_s_barrier(); \
    __builtin_amdgcn_sched_barrier(0); } while (0)

// ============ A: prep — cvt x, transpose-cvt wq/wk, wv2/bv2 ============
__global__ __launch_bounds__(256) void k_prep(
        const float* __restrict__ x, const float* __restrict__ wq, const float* __restrict__ wk,
        const float* __restrict__ wv, const float* __restrict__ bv, const float* __restrict__ wo,
        unsigned short* __restrict__ xb, unsigned short* __restrict__ wqt,
        unsigned short* __restrict__ wkt, float* __restrict__ wv2t, float* __restrict__ bv2) {
    __shared__ float t[32][33];
    int bx = blockIdx.x, tid = threadIdx.x;
    if (bx < 2048) {
        int i = bx * 256 + tid;
        float4 v = ((const float4*)x)[i];
        ushort4 o; o.x = f2bf(v.x); o.y = f2bf(v.y); o.z = f2bf(v.z); o.w = f2bf(v.w);
        ((ushort4*)xb)[i] = o;
    } else if (bx < 4096) {
        int g = bx - 2048; int z = g >> 10; g &= 1023;
        const float* src = z ? wk : wq;
        unsigned short* dst = z ? wkt : wqt;
        int be = (g & 31) * 32, bc = (g >> 5) * 32;
        int tx = tid & 31, ty = tid >> 5;
        #pragma unroll
        for (int yy = 0; yy < 32; yy += 8)
            t[ty + yy][tx] = src[(size_t)(be + ty + yy) * DMOD + bc + tx];
        __syncthreads();
        #pragma unroll
        for (int yy = 0; yy < 32; yy += 8)
            dst[(size_t)(bc + ty + yy) * DMOD + be + tx] = f2bf(t[tx][ty + yy]);
    } else {
        int g = bx - 4096;
        int grp = tid >> 6, l = tid & 63;
        int e = g * 4 + grp;
        float out = 0.f;
        #pragma unroll
        for (int it = 0; it < 16; ++it) {
            float v = wv[(size_t)e * DMOD + it * 64 + l] * wo[it * 64 + l];
            #pragma unroll
            for (int off = 1; off < 64; off <<= 1) v += __shfl_xor(v, off, 64);
            if (l == it) out = v;
        }
        if (l < 16) wv2t[l * DMOD + e] = out;
        if (g == 0 && grp == 0) {
            float ob = 0.f;
            #pragma unroll
            for (int it = 0; it < 16; ++it) {
                float v = bv[it * 64 + l] * wo[it * 64 + l];
                #pragma unroll
                for (int off = 1; off < 64; off <<= 1) v += __shfl_xor(v, off, 64);
                if (l == it) ob = v;
            }
            if (l < 16) bv2[l] = ob;
        }
    }
}

// ============ B: mid — u projection + Q/K MFMA GEMM, 128x128 m97 structure ============
__global__ __launch_bounds__(256, 3) void k_mid(
        const float* __restrict__ x, const float* __restrict__ wv2t, const float* __restrict__ bv2,
        const unsigned short* __restrict__ xb, const unsigned short* __restrict__ wqt,
        const unsigned short* __restrict__ wkt, const float* __restrict__ bq,
        const float* __restrict__ bk, float* __restrict__ u,
        unsigned short* __restrict__ qT, unsigned short* __restrict__ kT) {
    __shared__ unsigned short lA[128 * 64];
    __shared__ unsigned short lB[128 * 64];
    int bx = blockIdx.x, tid = threadIdx.x;
    if (bx >= 256) {
        int wave = (bx - 256) * 4 + (tid >> 6);
        int l = tid & 63;
        int b = wave >> 9, j = wave & 511;
        const float* xr = x + (size_t)(b * NSEQ + j) * DMOD;
        float p[16];
        #pragma unroll
        for (int h = 0; h < 16; ++h) p[h] = 0.f;
        for (int it = 0; it < 16; ++it) {
            int e = l + it * 64;
            float xv = xr[e];
            #pragma unroll
            for (int h = 0; h < 16; ++h) p[h] += xv * wv2t[h * DMOD + e];
        }
        #pragma unroll
        for (int h = 0; h < 16; ++h) {
            #pragma unroll
            for (int off = 1; off < 64; off <<= 1) p[h] += __shfl_xor(p[h], off, 64);
        }
        float out = 0.f;
        #pragma unroll
        for (int h = 0; h < 16; ++h) if (l == h) out = p[h] + bv2[h];
        if (l < 16) u[(b * 16 + l) * NSEQ + j] = out;
        return;
    }
    int g = bx;
    int mt = g & 15, nt8 = (g >> 4) & 7, z = g >> 7;
    const unsigned short* Wt = z ? wkt : wqt;
    const float* bias = z ? bk : bq;
    unsigned short* outT = z ? kT : qT;
    float scale = z ? 1.f : 0.125f;   // fold /sqrt(HD)=1/8 into q
    int m0 = mt * 128, n0 = nt8 * 128;
    int w = tid >> 6, lane = tid & 63;
    int wr = w >> 1, wc = w & 1;
    int quad = lane >> 4, cs = lane & 15;
    int l8 = lane >> 3, l7 = lane & 7;
    int sg = l7 ^ l8;                  // pre-swizzled source granule

    f32x4 acc[4][4];
    #pragma unroll
    for (int mi = 0; mi < 4; ++mi)
        #pragma unroll
        for (int ni = 0; ni < 4; ++ni) acc[mi][ni] = (f32x4){0.f, 0.f, 0.f, 0.f};

    for (int kc = 0; kc < 16; ++kc) {
        int k0 = kc * 64;
        #pragma unroll
        for (int q = 0; q < 4; ++q) {
            int row = w * 32 + q * 8 + l8;      // row&7 == l8 (base multiple of 8)
            gload_lds16(xb + (size_t)(m0 + row) * DMOD + k0 + sg * 8,
                        &lA[(w * 32 + q * 8) * 64]);
            gload_lds16(Wt + (size_t)(n0 + row) * DMOD + k0 + sg * 8,
                        &lB[(w * 32 + q * 8) * 64]);
        }
        __syncthreads();
        #pragma unroll
        for (int ks = 0; ks < 2; ++ks) {
            bf16x8 af[4], bfr[4];
            #pragma unroll
            for (int mi = 0; mi < 4; ++mi) {
                int row = wr * 64 + mi * 16 + cs;
                int gq = (ks * 4 + quad) ^ (row & 7);
                af[mi] = *(const bf16x8*)&lA[row * 64 + gq * 8];
            }
            #pragma unroll
            for (int ni = 0; ni < 4; ++ni) {
                int row = wc * 64 + ni * 16 + cs;
                int gq = (ks * 4 + quad) ^ (row & 7);
                bfr[ni] = *(const bf16x8*)&lB[row * 64 + gq * 8];
            }
            #pragma unroll
            for (int mi = 0; mi < 4; ++mi)
                #pragma unroll
                for (int ni = 0; ni < 4; ++ni)
                    acc[mi][ni] = __builtin_amdgcn_mfma_f32_16x16x32_bf16(
                        af[mi], bfr[ni], acc[mi][ni], 0, 0, 0);
        }
        __syncthreads();
    }
    #pragma unroll
    for (int ni = 0; ni < 4; ++ni) {
        int n = n0 + wc * 64 + ni * 16 + cs;
        int h = n >> 6, d = n & 63;
        float bvv = bias[n];
        #pragma unroll
        for (int mi = 0; mi < 4; ++mi) {
            #pragma unroll
            for (int rr = 0; rr < 4; ++rr) {
                int mg = m0 + wr * 64 + mi * 16 + quad * 4 + rr;
                int b = mg >> 9, i = mg & 511;
                outT[(size_t)((b * 16 + h) * NSEQ + i) * HD + d] =
                    f2bf((acc[mi][ni][rr] + bvv) * scale);
            }
        }
    }
}

// ============ C: fused attn — bias via global_load_lds DMA (no VGPR latency chains) ============
// grid (32 it, 8 jc, 8 bz): b = bz>>1, hg = bz&1; 512 thr = 8 waves; wave w -> h = hg*8+w.
// Each wave DMA-stages its OWN head's 16x64 bias tile to LDS (4 x 1KB global_load_lds;
// layout [4 grp][4 row][64] + 8 f32 pad per grp => max 2-way banks). rT4 = packed r+mask
// (proven 0-conflict). Own-wave bias needs only own-wave vmcnt(0), no extra barrier.
#define BGRP 264    // f32 stride of one 4-row bias group (4*64 + 8 pad)
#define BHEAD 1056  // 4 groups per head
__global__ __launch_bounds__(512, 4) void k_attn(
        const unsigned short* __restrict__ qT, const unsigned short* __restrict__ kT,
        const float* __restrict__ bias, const int* __restrict__ mask,
        const float* __restrict__ u, const float* __restrict__ r,
        float* __restrict__ spart, float* __restrict__ P) {
    __shared__ float bias_lds[8 * BHEAD];   // 33792 B
    __shared__ float rT4[16 * 64 * 4];      // 16384 B  (total 49 KiB -> 3 blocks/CU)
    int tid = threadIdx.x;
    int w = tid >> 6, lane = tid & 63;
    int quad = lane >> 4, col = lane & 15;
    int it = blockIdx.x, jc = blockIdx.y, bz = blockIdx.z;
    int b = bz >> 1, hg = bz & 1;
    int i0 = it * 16, j0 = jc * 64;
    int h = hg * 8 + w;
    int bh = b * 16 + h;

    // ---- 1: r/mask staging source loads (oldest in flight) ----
    float s0[2], s1[2], s2[2], smf[2];
    const float* rbase = r + (size_t)b * 3 * NSEQ * NSEQ;
    const int* mrow = mask + (size_t)b * NSEQ * NSEQ;
    #pragma unroll
    for (int t = 0; t < 2; ++t) {
        int slot = t * 512 + tid;
        int il = slot >> 6, jl = slot & 63;
        size_t off = (size_t)(i0 + il) * NSEQ + j0 + jl;
        s0[t] = rbase[off];
        s1[t] = rbase[(size_t)NSEQ * NSEQ + off];
        s2[t] = rbase[2 * (size_t)NSEQ * NSEQ + off];
        smf[t] = (float)mrow[off];
    }

    // ---- 2: Q/K/u register loads ----
    const unsigned short* qbase = qT + ((size_t)(bh * NSEQ + i0 + col)) * HD + quad * 8;
    bf16x8 a0 = *(const bf16x8*)qbase;
    bf16x8 a1 = *(const bf16x8*)(qbase + 32);
    bf16x8 kf0[4], kf1[4];
    #pragma unroll
    for (int jt = 0; jt < 4; ++jt) {
        const unsigned short* kbase =
            kT + ((size_t)(bh * NSEQ + j0 + jt * 16 + col)) * HD + quad * 8;
        kf0[jt] = *(const bf16x8*)kbase;
        kf1[jt] = *(const bf16x8*)(kbase + 32);
    }
    const float* ub = u + (size_t)bh * NSEQ;
    float uvv[4];
    #pragma unroll
    for (int jt = 0; jt < 4; ++jt) uvv[jt] = ub[j0 + jt * 16 + col];

    // ---- 3: bias tile DMA: 4 x 1KB, own head's 16x64 f32 ----
    {
        const float* bsrc = bias + (size_t)bh * NSEQ * NSEQ;
        int il4 = lane >> 4, jl4 = (lane & 15) * 4;
        #pragma unroll
        for (int g = 0; g < 4; ++g)
            gload_lds16f(bsrc + (size_t)(i0 + g * 4 + il4) * NSEQ + j0 + jl4,
                         &bias_lds[w * BHEAD + g * BGRP]);
    }

    // ---- 4: pack r+mask into LDS float4 (compiler waits only the oldest r loads) ----
    #pragma unroll
    for (int t = 0; t < 2; ++t) {
        int slot = t * 512 + tid;
        float4 pk; pk.x = s0[t]; pk.y = s1[t]; pk.z = s2[t]; pk.w = smf[t];
        *(float4*)&rT4[slot * 4] = pk;
    }

    // ---- 5: lgkm-only barrier (rT4 shared across waves) ----
    LGKM_BAR();
    // ---- 6: drain own wave's vmem (bias DMA + q/k/u regs); fence ds_reads below ----
    asm volatile("s_waitcnt vmcnt(0)" ::: "memory");
    __builtin_amdgcn_sched_barrier(0);

    // ---- 7: compute (one head per wave) ----
    const float* bwave = &bias_lds[w * BHEAD];
    float sp[4] = {0.f, 0.f, 0.f, 0.f};
    float pc0[4] = {0.f, 0.f, 0.f, 0.f};
    float pc1[4] = {0.f, 0.f, 0.f, 0.f};
    float pc2[4] = {0.f, 0.f, 0.f, 0.f};
    #pragma unroll
    for (int jt = 0; jt < 4; ++jt) {
        f32x4 acc = (f32x4){0.f, 0.f, 0.f, 0.f};
        acc = __builtin_amdgcn_mfma_f32_16x16x32_bf16(a0, kf0[jt], acc, 0, 0, 0);
        acc = __builtin_amdgcn_mfma_f32_16x16x32_bf16(a1, kf1[jt], acc, 0, 0, 0);
        float uv = uvv[jt];
        int jl = jt * 16 + col;
        #pragma unroll
        for (int rr = 0; rr < 4; ++rr) {
            int il = quad * 4 + rr;
            float4 v = *(const float4*)&rT4[(il * 64 + jl) * 4];
            float bvv = bwave[quad * BGRP + rr * 64 + jl];
            float lg = acc[rr] + bvv;
            float e = __expf(lg) * v.w;          // v.w = mask (0/1)
            sp[rr] += e;
            float eu = e * uv;
            pc0[rr] += eu * v.x;
            pc1[rr] += eu * v.y;
            pc2[rr] += eu * v.z;
        }
    }
    // reduce over the 16 col-lanes
    #pragma unroll
    for (int rr = 0; rr < 4; ++rr) {
        #pragma unroll
        for (int off = 1; off < 16; off <<= 1) {
            sp[rr]  += __shfl_xor(sp[rr], off, 64);
            pc0[rr] += __shfl_xor(pc0[rr], off, 64);
            pc1[rr] += __shfl_xor(pc1[rr], off, 64);
            pc2[rr] += __shfl_xor(pc2[rr], off, 64);
        }
    }
    if (col == 0) {
        #pragma unroll
        for (int rr = 0; rr < 4; ++rr) {
            int il = quad * 4 + rr;
            spart[((size_t)bh * NSEQ + i0 + il) * 8 + jc] = sp[rr];
            // P layout: [bh][it][il][jc][3] — jc innermost so k_final reads contiguous
            size_t pb = ((((size_t)bh * 32 + it) * 16 + il) * 8 + jc) * 3;
            P[pb + 0] = pc0[rr];
            P[pb + 1] = pc1[rr];
            P[pb + 2] = pc2[rr];
        }
    }
}

// ============ D: final — sinv + force (coalesced P reads) ============
// grid 128 = (b 4) x (it 32); block 256: il = tid&15 (contiguous P), h = tid>>4.
__global__ __launch_bounds__(256) void k_final(
        const float* __restrict__ spart, const float* __restrict__ P,
        const float* __restrict__ bo, float* __restrict__ out) {
    __shared__ float part[4][16][3];
    int bx = blockIdx.x;
    int b = bx >> 5, it = bx & 31;
    int tid = threadIdx.x;
    int il = tid & 15, h = tid >> 4;
    int w = tid >> 6;
    int bh = b * 16 + h;
    int i = it * 16 + il;
    const float* sprow = spart + ((size_t)bh * NSEQ + i) * 8;
    float4 sa = *(const float4*)sprow;
    float4 sb = *(const float4*)(sprow + 4);
    float s = sa.x + sa.y + sa.z + sa.w + sb.x + sb.y + sb.z + sb.w;
    float sinv = (s > 0.f) ? 1.f / s : 0.f;
    const float* pbase = P + (((size_t)bh * 32 + it) * 16 + il) * 24;
    float f[3] = {0.f, 0.f, 0.f};
    #pragma unroll
    for (int q = 0; q < 6; ++q) {
        float4 v = *(const float4*)(pbase + q * 4);
        f[(q * 4 + 0) % 3] += v.x;
        f[(q * 4 + 1) % 3] += v.y;
        f[(q * 4 + 2) % 3] += v.z;
        f[(q * 4 + 3) % 3] += v.w;
    }
    f[0] *= sinv; f[1] *= sinv; f[2] *= sinv;
    #pragma unroll
    for (int c = 0; c < 3; ++c) {
        f[c] += __shfl_xor(f[c], 16, 64);
        f[c] += __shfl_xor(f[c], 32, 64);
    }
    if ((tid & 48) == 0) {      // lane < 16 in each wave: holds sum over its 4 h values
        part[w][il][0] = f[0]; part[w][il][1] = f[1]; part[w][il][2] = f[2];
    }
    __syncthreads();
    if (tid < 16) {
        float bov = bo[0];
        float o0 = part[0][tid][0] + part[1][tid][0] + part[2][tid][0] + part[3][tid][0];
        float o1 = part[0][tid][1] + part[1][tid][1] + part[2][tid][1] + part[3][tid][1];
        float o2 = part[0][tid][2] + part[1][tid][2] + part[2][tid][2] + part[3][tid][2];
        size_t row = (size_t)b * NSEQ + it * 16 + tid;
        out[row * 3 + 0] = o0 + bov;
        out[row * 3 + 1] = o1 + bov;
        out[row * 3 + 2] = o2 + bov;
    }
}

extern "C" void kernel_launch(void* const* d_in, const int* in_sizes, int n_in,
                              void* d_out, int out_size, void* d_ws, size_t ws_size,
                              hipStream_t stream) {
    const float* x    = (const float*)d_in[0];
    const float* rr   = (const float*)d_in[1];
    const float* bias = (const float*)d_in[2];
    const int*   mask = (const int*)d_in[3];
    const float* wq   = (const float*)d_in[4];
    const float* bq   = (const float*)d_in[5];
    const float* wk   = (const float*)d_in[6];
    const float* bk   = (const float*)d_in[7];
    const float* wv   = (const float*)d_in[8];
    const float* bv   = (const float*)d_in[9];
    const float* wo   = (const float*)d_in[10];
    const float* bo   = (const float*)d_in[11];
    float* out = (float*)d_out;

    char* ws = (char*)d_ws;
    unsigned short* xb    = (unsigned short*)(ws + 0);          //  4 MiB
    unsigned short* wqt   = (unsigned short*)(ws + 4194304);    //  2 MiB
    unsigned short* wkt   = (unsigned short*)(ws + 6291456);    //  2 MiB
    float*          wv2t  = (float*)(ws + 8388608);             //  64 KiB
    float*          bv2   = (float*)(ws + 8454144);             //  256 B
    float*          u     = (float*)(ws + 8454400);             //  128 KiB
    unsigned short* qT    = (unsigned short*)(ws + 8585472);    //  4 MiB
    unsigned short* kT    = (unsigned short*)(ws + 12779776);   //  4 MiB
    float*          spart = (float*)(ws + 16974080);            //  1 MiB
    float*          P     = (float*)(ws + 18022656);            //  3 MiB
    // total ~21.2 MB

    k_prep<<<4352, 256, 0, stream>>>(x, wq, wk, wv, bv, wo, xb, wqt, wkt, wv2t, bv2);
    k_mid<<<768, 256, 0, stream>>>(x, wv2t, bv2, xb, wqt, wkt, bq, bk, u, qT, kT);
    k_attn<<<dim3(32, 8, 8), 512, 0, stream>>>(qT, kT, bias, mask, u, rr, spart, P);
    k_final<<<128, 256, 0, stream>>>(spart, P, bo, out);
}